// Round 11
// baseline (260.676 us; speedup 1.0000x reference)
//
#include <hip/hip_runtime.h>
#include <math.h>
#include <stdint.h>

#define N_TOK 16384
#define DM    4096
#define DH    2048
#define NE    64
#define TBG   32        // tokens per gemm block
#define TBE   64        // tokens per epilogue block
#define TOPK  4
#define NSTEP 32        // 1024 k per wave / 32

// out layout (all float32): topk_i [N,4] | topk_s [N,4] | scores [N,64] | aux_loss [1]
#define OFF_TI  0
#define OFF_TS  (N_TOK * TOPK)
#define OFF_SC  (N_TOK * TOPK * 2)
#define OFF_AUX (N_TOK * TOPK * 2 + N_TOK * NE)

typedef __attribute__((ext_vector_type(4)))  float  f32x4;
typedef __attribute__((ext_vector_type(16))) float  f32x16;
typedef __attribute__((ext_vector_type(8)))  __bf16 bf16x8;
typedef __attribute__((ext_vector_type(8)))  unsigned short u16x8;

// ws layout: Bws bf16 [0 .. 1.57MB) | esum f32 @ +1.57MB | pre f32 [2][N][64] @ 2MB (8MB)
#define BSPLIT_ELEMS (2 * 64 * 3 * 2 * 2 * 64 * 8)
#define PRE_BYTE_OFF (2u * 1024u * 1024u)

__device__ __forceinline__ void split3(float a, __bf16& h, __bf16& m, __bf16& l) {
    h = (__bf16)a;                 // a = h+m+l EXACT (24 = 8+8+8 mantissa bits)
    float r = a - (float)h;
    m = (__bf16)r;
    float r2 = r - (float)m;
    l = (__bf16)r2;
}

// One thread per (h, ks, et, sk, lane): split 8 consecutive k of one expert column,
// write 3 bf16x8 fragments in MFMA-fragment-major order.
// frag addr(h,ks,sp,et,sk) = (h*64+ks)*6144 + sp*2048 + et*1024 + sk*512 + lane*8
__global__ __launch_bounds__(256) void prep_B(
    const float* __restrict__ Ex, const float* __restrict__ Ey,
    __bf16* __restrict__ Bws)
{
    const int t    = blockIdx.x * 256 + threadIdx.x;   // 32768 threads
    const int lane = t & 63;
    const int sk   = (t >> 6) & 1;
    const int et   = (t >> 7) & 1;
    const int ks   = (t >> 8) & 63;
    const int h    = (t >> 14) & 1;
    const float* E = h ? Ey : Ex;
    const int e  = et * 32 + (lane & 31);
    const int k0 = ks * 32 + sk * 16 + (lane >> 5) * 8;
    bf16x8 vh, vm, vl;
    #pragma unroll
    for (int j = 0; j < 8; ++j) {
        __bf16 hh, mm, ll;
        split3(E[(size_t)(k0 + j) * NE + e], hh, mm, ll);
        vh[j] = hh; vm[j] = mm; vl[j] = ll;
    }
    #pragma unroll
    for (int s = 0; s < 3; ++s) {
        size_t base = ((((((size_t)h * 64 + ks) * 3 + s) * 2 + et) * 2 + sk) * 64 + lane) * 8;
        *(bf16x8*)(Bws + base) = (s == 0) ? vh : (s == 1) ? vm : vl;
    }
}

// 16 waves/CU: 4 blocks/CU x 4 waves. Wave = (et, kd): 32 tok x 32 exp x 1024 k.
__global__ __launch_bounds__(256, 4) void gemm_partial(
    const float* __restrict__ u, const __bf16* __restrict__ Bws,
    float* __restrict__ pre)
{
    __shared__ float part[2][TBG][36];    // [et][tok][e-in-half], 16B-aligned rows

    const int tid  = threadIdx.x;
    const int tile = blockIdx.x >> 1;
    const int h    = blockIdx.x & 1;      // model half (x / y)
    const int t0   = tile * TBG;
    const int lane = tid & 63;
    const int wv   = tid >> 6;            // 0..3
    const int et   = wv & 1;              // expert half
    const int kd   = wv >> 1;             // k-half of this h
    const int lr   = lane & 31;           // MFMA A-row (token) / B-col (expert)
    const int lkh  = lane >> 5;           // k-subgroup within fragment

    const float*  ap  = u + (size_t)(t0 + lr) * DM + h * DH + kd * 1024 + lkh * 8;
    const __bf16* bp0 = Bws + (size_t)(h * 64 + kd * 32) * 6144 + et * 1024 + lane * 8;

    f32x16 acc[2] = {};                   // [sk] independent chains
    f32x4  rA[2][4];                      // 2-deep static-indexed A prefetch

    auto loadA = [&](f32x4 (&r)[4], int s) {
        const float* p = ap + s * 32;
        r[0] = *(const f32x4*)(p);
        r[1] = *(const f32x4*)(p + 4);
        r[2] = *(const f32x4*)(p + 16);
        r[3] = *(const f32x4*)(p + 20);
    };

    auto body = [&](int s, f32x4 (&r)[4]) {
        // ---- 1) B(s): 6 fragment loads (L2-hot), oldest in vmcnt order ----
        const __bf16* bp = bp0 + (size_t)s * 6144;
        bf16x8 bh0 = *(const bf16x8*)(bp);
        bf16x8 bh1 = *(const bf16x8*)(bp + 512);
        bf16x8 bm0 = *(const bf16x8*)(bp + 2048);
        bf16x8 bm1 = *(const bf16x8*)(bp + 2560);
        bf16x8 bl0 = *(const bf16x8*)(bp + 4096);
        bf16x8 bl1 = *(const bf16x8*)(bp + 4608);
        __builtin_amdgcn_sched_barrier(0);
        // ---- 2) exact mask-based split of A(s) (VALU, covers B L2 latency) ----
        u16x8 sh[2], sm[2], sl[2];
        #pragma unroll
        for (int sk = 0; sk < 2; ++sk)
            #pragma unroll
            for (int q = 0; q < 2; ++q)
                #pragma unroll
                for (int j = 0; j < 4; ++j) {
                    float a = r[sk * 2 + q][j];
                    unsigned h32 = __float_as_uint(a) & 0xFFFF0000u;
                    float rr = a - __uint_as_float(h32);
                    unsigned m32 = __float_as_uint(rr) & 0xFFFF0000u;
                    float r2f = rr - __uint_as_float(m32);
                    sh[sk][q * 4 + j] = (unsigned short)(h32 >> 16);
                    sm[sk][q * 4 + j] = (unsigned short)(m32 >> 16);
                    sl[sk][q * 4 + j] = (unsigned short)(__float_as_uint(r2f) >> 16);
                }
        // ---- 3) A prefetch 2 steps ahead into the just-freed buffer (HBM) ----
        const int sp = (s + 2 < NSTEP) ? s + 2 : s;
        loadA(r, sp);
        __builtin_amdgcn_sched_barrier(0);
        // ---- 4) 6 exact products per sk; compiler's B-wait = vmcnt(4), A stays in flight ----
        {
            bf16x8 vh_ = __builtin_bit_cast(bf16x8, sh[0]);
            bf16x8 vm_ = __builtin_bit_cast(bf16x8, sm[0]);
            bf16x8 vl_ = __builtin_bit_cast(bf16x8, sl[0]);
            acc[0] = __builtin_amdgcn_mfma_f32_32x32x16_bf16(vh_, bh0, acc[0], 0, 0, 0);
            acc[0] = __builtin_amdgcn_mfma_f32_32x32x16_bf16(vm_, bh0, acc[0], 0, 0, 0);
            acc[0] = __builtin_amdgcn_mfma_f32_32x32x16_bf16(vl_, bh0, acc[0], 0, 0, 0);
            acc[0] = __builtin_amdgcn_mfma_f32_32x32x16_bf16(vh_, bm0, acc[0], 0, 0, 0);
            acc[0] = __builtin_amdgcn_mfma_f32_32x32x16_bf16(vm_, bm0, acc[0], 0, 0, 0);
            acc[0] = __builtin_amdgcn_mfma_f32_32x32x16_bf16(vh_, bl0, acc[0], 0, 0, 0);
        }
        {
            bf16x8 vh_ = __builtin_bit_cast(bf16x8, sh[1]);
            bf16x8 vm_ = __builtin_bit_cast(bf16x8, sm[1]);
            bf16x8 vl_ = __builtin_bit_cast(bf16x8, sl[1]);
            acc[1] = __builtin_amdgcn_mfma_f32_32x32x16_bf16(vh_, bh1, acc[1], 0, 0, 0);
            acc[1] = __builtin_amdgcn_mfma_f32_32x32x16_bf16(vm_, bh1, acc[1], 0, 0, 0);
            acc[1] = __builtin_amdgcn_mfma_f32_32x32x16_bf16(vl_, bh1, acc[1], 0, 0, 0);
            acc[1] = __builtin_amdgcn_mfma_f32_32x32x16_bf16(vh_, bm1, acc[1], 0, 0, 0);
            acc[1] = __builtin_amdgcn_mfma_f32_32x32x16_bf16(vm_, bm1, acc[1], 0, 0, 0);
            acc[1] = __builtin_amdgcn_mfma_f32_32x32x16_bf16(vh_, bl1, acc[1], 0, 0, 0);
        }
        __builtin_amdgcn_sched_barrier(0);
    };

    loadA(rA[0], 0);
    loadA(rA[1], 1);
    #pragma unroll 1
    for (int s = 0; s < NSTEP; s += 2) {
        body(s,     rA[0]);
        body(s + 1, rA[1]);
    }

    // ---- combine kd partials in LDS (deterministic), store pre[h][tok][e] ----
    // C/D layout: col=lane&31, row=(reg&3)+8*(reg>>2)+4*(lane>>5)
    f32x16 a = acc[0] + acc[1];
    __syncthreads();
    if (kd == 0) {
        #pragma unroll
        for (int q = 0; q < 4; ++q)
            #pragma unroll
            for (int j = 0; j < 4; ++j)
                part[et][j + 8 * q + 4 * lkh][lr] = a[q * 4 + j];
    }
    __syncthreads();
    if (kd == 1) {
        #pragma unroll
        for (int q = 0; q < 4; ++q)
            #pragma unroll
            for (int j = 0; j < 4; ++j)
                part[et][j + 8 * q + 4 * lkh][lr] += a[q * 4 + j];
    }
    __syncthreads();
    {
        const int tok = tid >> 3;
        const int e0  = (tid & 7) * 8;
        float* dst = pre + ((size_t)h * N_TOK + t0 + tok) * NE + e0;
        const float* src = &part[e0 >> 5][tok][e0 & 31];
        *(f32x4*)(dst)     = *(const f32x4*)(src);
        *(f32x4*)(dst + 4) = *(const f32x4*)(src + 4);
    }
}

__global__ __launch_bounds__(256) void torus_ep(
    const float* __restrict__ pre, const float* __restrict__ bias,
    const float* __restrict__ cp, const float* __restrict__ dp,
    const float* __restrict__ a1p, const float* __restrict__ b1p,
    float* __restrict__ out, float* __restrict__ esum)
{
    __shared__ float stile[TBE][NE + 1];
    __shared__ float s_m[TBE], s_inv[TBE];

    const int tid = threadIdx.x;
    const int t0  = blockIdx.x * TBE;

    // ---- pointwise torus map: thread = (tok, 16-expert slice) ----
    {
        const float c_ = *cp, d_ = *dp, a1_ = *a1p, b1_ = *b1p;
        const int tok = tid >> 2;
        const int e0  = (tid & 3) * 16;
        const float* px = pre + (size_t)(t0 + tok) * NE + e0;
        const float* py = pre + ((size_t)N_TOK + t0 + tok) * NE + e0;
        #pragma unroll
        for (int i = 0; i < 16; i += 4) {
            f32x4 xv = *(const f32x4*)(px + i);
            f32x4 yv = *(const f32x4*)(py + i);
            #pragma unroll
            for (int j = 0; j < 4; ++j) {
                int e = e0 + i + j;
                float x = tanhf(xv[j]) * 2.0f;
                float y = tanhf(yv[j]) * 2.0f;
                float xa = fabsf(x), ya = fabsf(y);
                float sc = (powf(xa, a1_) + powf(ya, b1_)) *
                           expf(-(powf(xa, c_) + powf(ya, d_))) + bias[e];
                stile[tok][e] = sc;
            }
        }
    }
    __syncthreads();

    // ---- per-token top-4 + softmax denom ----
    if (tid < TBE) {
        const int t = tid;
        float bv[TOPK]; int bi[TOPK];
        #pragma unroll
        for (int p = 0; p < TOPK; ++p) {
            float best = -INFINITY; int besti = 0;
            for (int e = 0; e < NE; ++e) {
                float v = stile[t][e];
                bool taken = false;
                #pragma unroll
                for (int q = 0; q < p; ++q) taken = taken || (bi[q] == e);
                if (!taken && v > best) { best = v; besti = e; }  // strict > == lax.top_k tie-break
            }
            bv[p] = best; bi[p] = besti;
        }
        const float m = bv[0];
        float denom = 0.0f;
        for (int e = 0; e < NE; ++e) denom += expf(stile[t][e] - m);
        const float inv = 1.0f / denom;
        s_m[t] = m; s_inv[t] = inv;
        #pragma unroll
        for (int p = 0; p < TOPK; ++p) {
            out[OFF_TI + (size_t)(t0 + t) * TOPK + p] = (float)bi[p];
            out[OFF_TS + (size_t)(t0 + t) * TOPK + p] = bv[p];
        }
    }
    __syncthreads();

    // ---- per-expert prob column-sums -> global accumulate ----
    if (tid < NE) {
        const int e = tid;
        float cs = 0.0f;
        for (int t = 0; t < TBE; ++t)
            cs += expf(stile[t][e] - s_m[t]) * s_inv[t];
        atomicAdd(&esum[e], cs);
    }

    // ---- scores -> global, coalesced ----
    for (int idx = tid; idx < TBE * NE; idx += 256)
        out[OFF_SC + (size_t)t0 * NE + idx] = stile[idx >> 6][idx & (NE - 1)];
}

__global__ __launch_bounds__(64) void torus_aux(const float* __restrict__ esum,
                                                float* __restrict__ out)
{
    const int e = threadIdx.x;
    float s = esum[e] * (1.0f / (float)N_TOK);
    float v = s * s;
    #pragma unroll
    for (int off = 32; off > 0; off >>= 1) v += __shfl_down(v, off);
    if (e == 0) out[OFF_AUX] = v * (float)NE;
}

extern "C" void kernel_launch(void* const* d_in, const int* in_sizes, int n_in,
                              void* d_out, int out_size, void* d_ws, size_t ws_size,
                              hipStream_t stream) {
    const float* u    = (const float*)d_in[0];
    const float* Ex   = (const float*)d_in[1];
    const float* Ey   = (const float*)d_in[2];
    const float* bias = (const float*)d_in[3];
    const float* cp   = (const float*)d_in[4];
    const float* dp   = (const float*)d_in[5];
    const float* a1p  = (const float*)d_in[6];
    const float* b1p  = (const float*)d_in[7];
    float* out  = (float*)d_out;
    __bf16* Bws = (__bf16*)d_ws;
    float* esum = (float*)((char*)d_ws + (size_t)BSPLIT_ELEMS * sizeof(__bf16));
    float* pre  = (float*)((char*)d_ws + PRE_BYTE_OFF);   // [2][N_TOK][64] fp32, 8 MB

    prep_B<<<128, 256, 0, stream>>>(Ex, Ey, Bws);
    hipMemsetAsync(esum, 0, NE * sizeof(float), stream);
    gemm_partial<<<N_TOK / TBG * 2, 256, 0, stream>>>(u, Bws, pre);
    torus_ep<<<N_TOK / TBE, 256, 0, stream>>>(pre, bias, cp, dp, a1p, b1p, out, esum);
    torus_aux<<<1, 64, 0, stream>>>(esum, out);
}

// Round 12
// 172.778 us; speedup vs baseline: 1.5087x; 1.5087x over previous
//
#include <hip/hip_runtime.h>
#include <math.h>
#include <stdint.h>

#define N_TOK 16384
#define DM    4096
#define DH    2048
#define NE    64
#define TBG   32        // tokens per gemm tile
#define TBE   64        // tokens per epilogue block
#define TOPK  4
#define NSTEP 32        // 1024 k per wave / 32

// out layout (all float32): topk_i [N,4] | topk_s [N,4] | scores [N,64] | aux_loss [1]
#define OFF_TI  0
#define OFF_TS  (N_TOK * TOPK)
#define OFF_SC  (N_TOK * TOPK * 2)
#define OFF_AUX (N_TOK * TOPK * 2 + N_TOK * NE)

typedef __attribute__((ext_vector_type(4)))  float  f32x4;
typedef __attribute__((ext_vector_type(16))) float  f32x16;
typedef __attribute__((ext_vector_type(8)))  __bf16 bf16x8;
typedef __attribute__((ext_vector_type(8)))  unsigned short u16x8;

// ws layout: Bws bf16 [0..1.57MB) | esum f32 @ +1.57MB | pre f32 [kd2][h2][N][64] @ 2MB (16MB)
#define BSPLIT_ELEMS (2 * 64 * 3 * 2 * 2 * 64 * 8)
#define PRE_BYTE_OFF (2u * 1024u * 1024u)

__device__ __forceinline__ void split3(float a, __bf16& h, __bf16& m, __bf16& l) {
    h = (__bf16)a;                 // a = h+m+l EXACT (24 = 8+8+8 mantissa bits)
    float r = a - (float)h;
    m = (__bf16)r;
    float r2 = r - (float)m;
    l = (__bf16)r2;
}

// One thread per (h, ks, et, sk, lane): split 8 consecutive k of one expert column,
// write 3 bf16x8 fragments in MFMA-fragment-major order.
// frag addr(h,ks,sp,et,sk) = (h*64+ks)*6144 + sp*2048 + et*1024 + sk*512 + lane*8
__global__ __launch_bounds__(256) void prep_B(
    const float* __restrict__ Ex, const float* __restrict__ Ey,
    __bf16* __restrict__ Bws)
{
    const int t    = blockIdx.x * 256 + threadIdx.x;   // 32768 threads
    const int lane = t & 63;
    const int sk   = (t >> 6) & 1;
    const int et   = (t >> 7) & 1;
    const int ks   = (t >> 8) & 63;
    const int h    = (t >> 14) & 1;
    const float* E = h ? Ey : Ex;
    const int e  = et * 32 + (lane & 31);
    const int k0 = ks * 32 + sk * 16 + (lane >> 5) * 8;
    bf16x8 vh, vm, vl;
    #pragma unroll
    for (int j = 0; j < 8; ++j) {
        __bf16 hh, mm, ll;
        split3(E[(size_t)(k0 + j) * NE + e], hh, mm, ll);
        vh[j] = hh; vm[j] = mm; vl[j] = ll;
    }
    #pragma unroll
    for (int s = 0; s < 3; ++s) {
        size_t base = ((((((size_t)h * 64 + ks) * 3 + s) * 2 + et) * 2 + sk) * 64 + lane) * 8;
        *(bf16x8*)(Bws + base) = (s == 0) ? vh : (s == 1) ? vm : vl;
    }
}

// 2-wave blocks; wave = et. Block = (tile, h, kd). 2048 blocks = 4096 waves = 16/CU.
// Register budget target: <=128 TOTAL (VGPR+AGPR unified, 512/4 waves-per-EU).
__global__ __launch_bounds__(128, 4) void gemm_partial(
    const float* __restrict__ u, const __bf16* __restrict__ Bws,
    float* __restrict__ pre)
{
    const int tid  = threadIdx.x;
    const int lane = tid & 63;
    const int et   = tid >> 6;            // wave id = expert half
    const int bid  = blockIdx.x;
    const int kd   = bid & 1;             // k-half of the model half
    const int h    = (bid >> 1) & 1;      // model half (x / y)
    const int tile = bid >> 2;
    const int t0   = tile * TBG;
    const int lr   = lane & 31;           // MFMA A-row (token) / B-col (expert)
    const int lkh  = lane >> 5;           // k-subgroup within fragment

    const float*  ap  = u + (size_t)(t0 + lr) * DM + h * DH + kd * 1024 + lkh * 8;
    const __bf16* bp0 = Bws + (size_t)(h * 64 + kd * 32) * 6144 + et * 1024 + lane * 8;

    f32x16 acc0 = {}, acc1 = {};          // sk0 / sk1 chains (32 regs)
    f32x4 r0, r1, r2, r3;                 // single A buffer (16 regs), 1-step prefetch

    r0 = *(const f32x4*)(ap);
    r1 = *(const f32x4*)(ap + 4);
    r2 = *(const f32x4*)(ap + 16);
    r3 = *(const f32x4*)(ap + 20);

    #pragma unroll 1
    for (int s = 0; s < NSTEP; ++s) {
        // ---- 1) B(s): 6 fragment loads (L2-hot), oldest in vmcnt order ----
        const __bf16* bp = bp0 + (size_t)s * 6144;
        bf16x8 bh0 = *(const bf16x8*)(bp);
        bf16x8 bh1 = *(const bf16x8*)(bp + 512);
        bf16x8 bm0 = *(const bf16x8*)(bp + 2048);
        bf16x8 bm1 = *(const bf16x8*)(bp + 2560);
        bf16x8 bl0 = *(const bf16x8*)(bp + 4096);
        bf16x8 bl1 = *(const bf16x8*)(bp + 4608);
        __builtin_amdgcn_sched_barrier(0);
        // ---- 2) exact mask-based split of A(s); r dies into splits ----
        u16x8 sh0, sm0, sl0, sh1, sm1, sl1;
        #pragma unroll
        for (int q = 0; q < 2; ++q)
            #pragma unroll
            for (int j = 0; j < 4; ++j) {
                {
                    float a = (q == 0 ? r0 : r1)[j];
                    unsigned h32 = __float_as_uint(a) & 0xFFFF0000u;
                    float rr = a - __uint_as_float(h32);
                    unsigned m32 = __float_as_uint(rr) & 0xFFFF0000u;
                    float r2f = rr - __uint_as_float(m32);
                    sh0[q * 4 + j] = (unsigned short)(h32 >> 16);
                    sm0[q * 4 + j] = (unsigned short)(m32 >> 16);
                    sl0[q * 4 + j] = (unsigned short)(__float_as_uint(r2f) >> 16);
                }
                {
                    float a = (q == 0 ? r2 : r3)[j];
                    unsigned h32 = __float_as_uint(a) & 0xFFFF0000u;
                    float rr = a - __uint_as_float(h32);
                    unsigned m32 = __float_as_uint(rr) & 0xFFFF0000u;
                    float r2f = rr - __uint_as_float(m32);
                    sh1[q * 4 + j] = (unsigned short)(h32 >> 16);
                    sm1[q * 4 + j] = (unsigned short)(m32 >> 16);
                    sl1[q * 4 + j] = (unsigned short)(__float_as_uint(r2f) >> 16);
                }
            }
        // ---- 3) A(s+1) prefetch into the just-freed buffer (HBM, 1 body lead) ----
        {
            const float* pn = ap + ((s + 1 < NSTEP) ? s + 1 : s) * 32;
            r0 = *(const f32x4*)(pn);
            r1 = *(const f32x4*)(pn + 4);
            r2 = *(const f32x4*)(pn + 16);
            r3 = *(const f32x4*)(pn + 20);
        }
        __builtin_amdgcn_sched_barrier(0);
        // ---- 4) 6 exact products per sk; MFMA's B-wait (vmcnt 4) leaves A(s+1) in flight ----
        {
            bf16x8 vh_ = __builtin_bit_cast(bf16x8, sh0);
            bf16x8 vm_ = __builtin_bit_cast(bf16x8, sm0);
            bf16x8 vl_ = __builtin_bit_cast(bf16x8, sl0);
            acc0 = __builtin_amdgcn_mfma_f32_32x32x16_bf16(vh_, bh0, acc0, 0, 0, 0);
            acc0 = __builtin_amdgcn_mfma_f32_32x32x16_bf16(vm_, bh0, acc0, 0, 0, 0);
            acc0 = __builtin_amdgcn_mfma_f32_32x32x16_bf16(vl_, bh0, acc0, 0, 0, 0);
            acc0 = __builtin_amdgcn_mfma_f32_32x32x16_bf16(vh_, bm0, acc0, 0, 0, 0);
            acc0 = __builtin_amdgcn_mfma_f32_32x32x16_bf16(vm_, bm0, acc0, 0, 0, 0);
            acc0 = __builtin_amdgcn_mfma_f32_32x32x16_bf16(vh_, bl0, acc0, 0, 0, 0);
        }
        {
            bf16x8 vh_ = __builtin_bit_cast(bf16x8, sh1);
            bf16x8 vm_ = __builtin_bit_cast(bf16x8, sm1);
            bf16x8 vl_ = __builtin_bit_cast(bf16x8, sl1);
            acc1 = __builtin_amdgcn_mfma_f32_32x32x16_bf16(vh_, bh1, acc1, 0, 0, 0);
            acc1 = __builtin_amdgcn_mfma_f32_32x32x16_bf16(vm_, bh1, acc1, 0, 0, 0);
            acc1 = __builtin_amdgcn_mfma_f32_32x32x16_bf16(vl_, bh1, acc1, 0, 0, 0);
            acc1 = __builtin_amdgcn_mfma_f32_32x32x16_bf16(vh_, bm1, acc1, 0, 0, 0);
            acc1 = __builtin_amdgcn_mfma_f32_32x32x16_bf16(vm_, bm1, acc1, 0, 0, 0);
            acc1 = __builtin_amdgcn_mfma_f32_32x32x16_bf16(vh_, bl1, acc1, 0, 0, 0);
        }
        __builtin_amdgcn_sched_barrier(0);
    }

    // ---- store kd-partials: pre[kd][h][t0+row][et*32+lr] ----
    // C/D layout: col=lane&31, row=(reg&3)+8*(reg>>2)+4*(lane>>5)
    f32x16 a = acc0 + acc1;
    float* dst = pre + (((size_t)kd * 2 + h) * N_TOK + t0) * NE + et * 32 + lr;
    #pragma unroll
    for (int q = 0; q < 4; ++q)
        #pragma unroll
        for (int j = 0; j < 4; ++j)
            dst[(size_t)(j + 8 * q + 4 * lkh) * NE] = a[q * 4 + j];
}

__global__ __launch_bounds__(256) void torus_ep(
    const float* __restrict__ pre, const float* __restrict__ bias,
    const float* __restrict__ cp, const float* __restrict__ dp,
    const float* __restrict__ a1p, const float* __restrict__ b1p,
    float* __restrict__ out, float* __restrict__ esum)
{
    __shared__ float stile[TBE][NE + 1];
    __shared__ float s_m[TBE], s_inv[TBE];

    const int tid = threadIdx.x;
    const int t0  = blockIdx.x * TBE;

    // ---- pointwise torus map: thread = (tok, 16-expert slice); sum kd partials ----
    {
        const float c_ = *cp, d_ = *dp, a1_ = *a1p, b1_ = *b1p;
        const int tok = tid >> 2;
        const int e0  = (tid & 3) * 16;
        const float* p00 = pre + ((size_t)0 * N_TOK + t0 + tok) * NE + e0;  // kd0,h0
        const float* p01 = pre + ((size_t)1 * N_TOK + t0 + tok) * NE + e0;  // kd0,h1
        const float* p10 = pre + ((size_t)2 * N_TOK + t0 + tok) * NE + e0;  // kd1,h0
        const float* p11 = pre + ((size_t)3 * N_TOK + t0 + tok) * NE + e0;  // kd1,h1
        #pragma unroll
        for (int i = 0; i < 16; i += 4) {
            f32x4 xv = *(const f32x4*)(p00 + i);
            f32x4 x2 = *(const f32x4*)(p10 + i);
            f32x4 yv = *(const f32x4*)(p01 + i);
            f32x4 y2 = *(const f32x4*)(p11 + i);
            #pragma unroll
            for (int j = 0; j < 4; ++j) {
                int e = e0 + i + j;
                float x = tanhf(xv[j] + x2[j]) * 2.0f;
                float y = tanhf(yv[j] + y2[j]) * 2.0f;
                float xa = fabsf(x), ya = fabsf(y);
                float sc = (powf(xa, a1_) + powf(ya, b1_)) *
                           expf(-(powf(xa, c_) + powf(ya, d_))) + bias[e];
                stile[tok][e] = sc;
            }
        }
    }
    __syncthreads();

    // ---- per-token top-4 + softmax denom ----
    if (tid < TBE) {
        const int t = tid;
        float bv[TOPK]; int bi[TOPK];
        #pragma unroll
        for (int p = 0; p < TOPK; ++p) {
            float best = -INFINITY; int besti = 0;
            for (int e = 0; e < NE; ++e) {
                float v = stile[t][e];
                bool taken = false;
                #pragma unroll
                for (int q = 0; q < p; ++q) taken = taken || (bi[q] == e);
                if (!taken && v > best) { best = v; besti = e; }  // strict > == lax.top_k tie-break
            }
            bv[p] = best; bi[p] = besti;
        }
        const float m = bv[0];
        float denom = 0.0f;
        for (int e = 0; e < NE; ++e) denom += expf(stile[t][e] - m);
        const float inv = 1.0f / denom;
        s_m[t] = m; s_inv[t] = inv;
        #pragma unroll
        for (int p = 0; p < TOPK; ++p) {
            out[OFF_TI + (size_t)(t0 + t) * TOPK + p] = (float)bi[p];
            out[OFF_TS + (size_t)(t0 + t) * TOPK + p] = bv[p];
        }
    }
    __syncthreads();

    // ---- per-expert prob column-sums -> global accumulate ----
    if (tid < NE) {
        const int e = tid;
        float cs = 0.0f;
        for (int t = 0; t < TBE; ++t)
            cs += expf(stile[t][e] - s_m[t]) * s_inv[t];
        atomicAdd(&esum[e], cs);
    }

    // ---- scores -> global, coalesced ----
    for (int idx = tid; idx < TBE * NE; idx += 256)
        out[OFF_SC + (size_t)t0 * NE + idx] = stile[idx >> 6][idx & (NE - 1)];
}

__global__ __launch_bounds__(64) void torus_aux(const float* __restrict__ esum,
                                                float* __restrict__ out)
{
    const int e = threadIdx.x;
    float s = esum[e] * (1.0f / (float)N_TOK);
    float v = s * s;
    #pragma unroll
    for (int off = 32; off > 0; off >>= 1) v += __shfl_down(v, off);
    if (e == 0) out[OFF_AUX] = v * (float)NE;
}

extern "C" void kernel_launch(void* const* d_in, const int* in_sizes, int n_in,
                              void* d_out, int out_size, void* d_ws, size_t ws_size,
                              hipStream_t stream) {
    const float* u    = (const float*)d_in[0];
    const float* Ex   = (const float*)d_in[1];
    const float* Ey   = (const float*)d_in[2];
    const float* bias = (const float*)d_in[3];
    const float* cp   = (const float*)d_in[4];
    const float* dp   = (const float*)d_in[5];
    const float* a1p  = (const float*)d_in[6];
    const float* b1p  = (const float*)d_in[7];
    float* out  = (float*)d_out;
    __bf16* Bws = (__bf16*)d_ws;
    float* esum = (float*)((char*)d_ws + (size_t)BSPLIT_ELEMS * sizeof(__bf16));
    float* pre  = (float*)((char*)d_ws + PRE_BYTE_OFF);   // [2][2][N_TOK][64] fp32, 16 MB

    prep_B<<<128, 256, 0, stream>>>(Ex, Ey, Bws);
    hipMemsetAsync(esum, 0, NE * sizeof(float), stream);
    gemm_partial<<<N_TOK / TBG * 4, 128, 0, stream>>>(u, Bws, pre);
    torus_ep<<<N_TOK / TBE, 256, 0, stream>>>(pre, bias, cp, dp, a1p, b1p, out, esum);
    torus_aux<<<1, 64, 0, stream>>>(esum, out);
}

// Round 13
// 127.481 us; speedup vs baseline: 2.0448x; 1.3553x over previous
//
#include <hip/hip_runtime.h>
#include <math.h>
#include <stdint.h>

#define N_TOK 16384
#define DM    4096
#define DH    2048
#define NE    64
#define TBE   64
#define TOPK  4
#define NST   16        // K=2048 per half / 128 per step

// out layout (all float32): topk_i [N,4] | topk_s [N,4] | scores [N,64] | aux_loss [1]
#define OFF_TI  0
#define OFF_TS  (N_TOK * TOPK)
#define OFF_SC  (N_TOK * TOPK * 2)
#define OFF_AUX (N_TOK * TOPK * 2 + N_TOK * NE)

typedef __attribute__((ext_vector_type(4)))  float  f32x4;
typedef __attribute__((ext_vector_type(16))) float  f32x16;
typedef __attribute__((ext_vector_type(8)))  __bf16 bf16x8;
typedef __attribute__((ext_vector_type(8)))  unsigned short u16x8;

// ws layout: Bws bf16 [0..1.5MB) | esum f32 | pre f32 [h2][N][64] @ 2MB (8MB)
#define BSPLIT_ELEMS (2 * 64 * 3 * 2 * 2 * 64 * 8)
#define PRE_BYTE_OFF (2u * 1024u * 1024u)

__device__ __forceinline__ void split3(float a, __bf16& h, __bf16& m, __bf16& l) {
    h = (__bf16)a;
    float r = a - (float)h;
    m = (__bf16)r;
    float r2 = r - (float)m;
    l = (__bf16)r2;
}

__device__ __forceinline__ void stage16(const float* g, void* l) {
    __builtin_amdgcn_global_load_lds(
        (const __attribute__((address_space(1))) unsigned int*)(uintptr_t)g,
        (__attribute__((address_space(3))) unsigned int*)(uintptr_t)l,
        16, 0, 0);
}

// exact mask split of one f32x4 pair -> three u16x8 (sk fragment)
__device__ __forceinline__ void splitPair(const f32x4& lo, const f32x4& hi,
                                          u16x8& sh, u16x8& sm, u16x8& sl) {
    #pragma unroll
    for (int q = 0; q < 2; ++q)
        #pragma unroll
        for (int j = 0; j < 4; ++j) {
            float a = (q == 0 ? lo : hi)[j];
            unsigned h32 = __float_as_uint(a) & 0xFFFF0000u;
            float rr = a - __uint_as_float(h32);
            unsigned m32 = __float_as_uint(rr) & 0xFFFF0000u;
            float r2f = rr - __uint_as_float(m32);
            sh[q * 4 + j] = (unsigned short)(h32 >> 16);
            sm[q * 4 + j] = (unsigned short)(m32 >> 16);
            sl[q * 4 + j] = (unsigned short)(__float_as_uint(r2f) >> 16);
        }
}

// prep_B unchanged: fragment-major [h][ks64]{12288B}: sp*4096 + et*2048 + sk*1024 + lane*16
__global__ __launch_bounds__(256) void prep_B(
    const float* __restrict__ Ex, const float* __restrict__ Ey,
    __bf16* __restrict__ Bws)
{
    const int t    = blockIdx.x * 256 + threadIdx.x;
    const int lane = t & 63;
    const int sk   = (t >> 6) & 1;
    const int et   = (t >> 7) & 1;
    const int ks   = (t >> 8) & 63;
    const int h    = (t >> 14) & 1;
    const float* E = h ? Ey : Ex;
    const int e  = et * 32 + (lane & 31);
    const int k0 = ks * 32 + sk * 16 + (lane >> 5) * 8;
    bf16x8 vh, vm, vl;
    #pragma unroll
    for (int j = 0; j < 8; ++j) {
        __bf16 hh, mm, ll;
        split3(E[(size_t)(k0 + j) * NE + e], hh, mm, ll);
        vh[j] = hh; vm[j] = mm; vl[j] = ll;
    }
    #pragma unroll
    for (int s = 0; s < 3; ++s) {
        size_t base = ((((((size_t)h * 64 + ks) * 3 + s) * 2 + et) * 2 + sk) * 64 + lane) * 8;
        *(bf16x8*)(Bws + base) = (s == 0) ? vh : (s == 1) ? vm : vl;
    }
}

// 4 waves/block, 1 block/CU (128KB LDS). Wave = 32 tok x 64 exp x K=2048(full half).
// K-step 128: 512-B contiguous row bursts via global_load_lds; all waits hand-counted.
__global__ __launch_bounds__(256, 1) void gemm_half(
    const float* __restrict__ u, const __bf16* __restrict__ Bws,
    float* __restrict__ pre)
{
    __shared__ __align__(16) unsigned char aring[4][2][16384];  // [wave][slot][32 rows x 512B]

    const int tid  = threadIdx.x;
    const int lane = tid & 63;
    const int wv   = tid >> 6;           // 0..3 token group
    const int h    = blockIdx.x & 1;
    const int tile = blockIdx.x >> 1;
    const int t0   = tile * 128;
    const int lr   = lane & 31;          // MFMA A-row / B-col
    const int lkh  = lane >> 5;          // k-subgroup
    const int hb   = lane >> 5;          // staging row-half

    // staging source base: row_local = 2i + hb, chunk = (lane&31) ^ (row_local&7)
    const float* uw = u + (size_t)(t0 + wv * 32 + hb) * DM + h * DH;
    const unsigned ldsW = (unsigned)(uintptr_t)(void*)&aring[wv][0][0];
    const char* bwsB = (const char*)Bws + (size_t)(h * 64) * 12288 + lane * 16;

    f32x16 acc0 = {}, acc1 = {};

    auto stageA = [&](int s, int slot) {
        const float* gb = uw + s * 128;
        unsigned char* d = &aring[wv][slot][0];
        #pragma unroll
        for (int i = 0; i < 16; ++i) {
            const int m = ((2 * i) & 7) | hb;             // = (2i+hb)&7
            const float* g = gb + (size_t)(2 * i) * DM + (((lane & 31) ^ m) * 4);
            stage16(g, d + i * 1024);
        }
    };

    // prologue: stage step 0 into slot 0
    stageA(0, 0);
    __builtin_amdgcn_sched_barrier(0);

    #pragma unroll 1
    for (int s = 0; s < NST; ++s) {
        f32x4 bb[4][12];
        // 1) issue all 48 B(s) fragment loads (L2-hot), inline asm
        #pragma unroll
        for (int c = 0; c < 4; ++c) {
            const char* bc = bwsB + (size_t)(s * 4 + c) * 12288;
            #pragma unroll
            for (int sp = 0; sp < 3; ++sp) {
                uint64_t ad = (uint64_t)(uintptr_t)(bc + sp * 4096);
                asm volatile(
                    "global_load_dwordx4 %0, %4, off\n\t"
                    "global_load_dwordx4 %1, %4, off offset:1024\n\t"
                    "global_load_dwordx4 %2, %4, off offset:2048\n\t"
                    "global_load_dwordx4 %3, %4, off offset:3072"
                    : "=&v"(bb[c][sp * 4 + 0]), "=&v"(bb[c][sp * 4 + 1]),
                      "=&v"(bb[c][sp * 4 + 2]), "=&v"(bb[c][sp * 4 + 3])
                    : "v"(ad));
            }
        }
        __builtin_amdgcn_sched_barrier(0);
        // 2) stage(s) landed: exactly the 48 B(s) loads are newer
        asm volatile("s_waitcnt vmcnt(48)" ::: "memory");
        __builtin_amdgcn_sched_barrier(0);
        // 3) deep-prefetch stage(s+1) (16 vmem; stays in flight across the step)
        stageA(s + 1 < NST ? s + 1 : NST - 1, (s + 1) & 1);
        __builtin_amdgcn_sched_barrier(0);

        // 4) four k32 clusters: ds_read A raw -> split -> counted B wait -> 24 MFMA
        const unsigned ab = ldsW + (unsigned)((s & 1) * 16384) + (unsigned)lr * 512;
        const unsigned xr = (unsigned)(lr & 7);
        #pragma unroll
        for (int c = 0; c < 4; ++c) {
            const unsigned a = (unsigned)(c * 8 + lkh * 2);
            unsigned ad0 = ab + (((a    ) ^ xr) << 4);
            unsigned ad1 = ab + (((a + 1) ^ xr) << 4);
            unsigned ad2 = ab + (((a + 4) ^ xr) << 4);
            unsigned ad3 = ab + (((a + 5) ^ xr) << 4);
            f32x4 r0, r1, r2, r3;
            asm volatile(
                "ds_read_b128 %0, %4\n\t"
                "ds_read_b128 %1, %5\n\t"
                "ds_read_b128 %2, %6\n\t"
                "ds_read_b128 %3, %7\n\t"
                "s_waitcnt lgkmcnt(0)"
                : "=&v"(r0), "=&v"(r1), "=&v"(r2), "=&v"(r3)
                : "v"(ad0), "v"(ad1), "v"(ad2), "v"(ad3));
            __builtin_amdgcn_sched_barrier(0);
            u16x8 sh0, sm0, sl0, sh1, sm1, sl1;
            splitPair(r0, r1, sh0, sm0, sl0);
            splitPair(r2, r3, sh1, sm1, sl1);
            __builtin_amdgcn_sched_barrier(0);
            // bb[c] retired: newer = bb[c+1..3] (36-12c) + stage(s+1) 16
            if      (c == 0) asm volatile("s_waitcnt vmcnt(52)" ::: "memory");
            else if (c == 1) asm volatile("s_waitcnt vmcnt(40)" ::: "memory");
            else if (c == 2) asm volatile("s_waitcnt vmcnt(28)" ::: "memory");
            else             asm volatile("s_waitcnt vmcnt(16)" ::: "memory");
            __builtin_amdgcn_sched_barrier(0);
            // 24 MFMA: frag idx = sp*4 + et*2 + sk; products {h,m,l}x bh, {h,m}x bm, {h}x bl
            {
                bf16x8 vh = __builtin_bit_cast(bf16x8, sh0);
                bf16x8 vm = __builtin_bit_cast(bf16x8, sm0);
                bf16x8 vl = __builtin_bit_cast(bf16x8, sl0);
                bf16x8 Bh = __builtin_bit_cast(bf16x8, bb[c][0]);
                bf16x8 Bm = __builtin_bit_cast(bf16x8, bb[c][4]);
                bf16x8 Bl = __builtin_bit_cast(bf16x8, bb[c][8]);
                acc0 = __builtin_amdgcn_mfma_f32_32x32x16_bf16(vh, Bh, acc0, 0, 0, 0);
                acc0 = __builtin_amdgcn_mfma_f32_32x32x16_bf16(vm, Bh, acc0, 0, 0, 0);
                acc0 = __builtin_amdgcn_mfma_f32_32x32x16_bf16(vl, Bh, acc0, 0, 0, 0);
                acc0 = __builtin_amdgcn_mfma_f32_32x32x16_bf16(vh, Bm, acc0, 0, 0, 0);
                acc0 = __builtin_amdgcn_mfma_f32_32x32x16_bf16(vm, Bm, acc0, 0, 0, 0);
                acc0 = __builtin_amdgcn_mfma_f32_32x32x16_bf16(vh, Bl, acc0, 0, 0, 0);
                Bh = __builtin_bit_cast(bf16x8, bb[c][2]);
                Bm = __builtin_bit_cast(bf16x8, bb[c][6]);
                Bl = __builtin_bit_cast(bf16x8, bb[c][10]);
                acc1 = __builtin_amdgcn_mfma_f32_32x32x16_bf16(vh, Bh, acc1, 0, 0, 0);
                acc1 = __builtin_amdgcn_mfma_f32_32x32x16_bf16(vm, Bh, acc1, 0, 0, 0);
                acc1 = __builtin_amdgcn_mfma_f32_32x32x16_bf16(vl, Bh, acc1, 0, 0, 0);
                acc1 = __builtin_amdgcn_mfma_f32_32x32x16_bf16(vh, Bm, acc1, 0, 0, 0);
                acc1 = __builtin_amdgcn_mfma_f32_32x32x16_bf16(vm, Bm, acc1, 0, 0, 0);
                acc1 = __builtin_amdgcn_mfma_f32_32x32x16_bf16(vh, Bl, acc1, 0, 0, 0);
            }
            {
                bf16x8 vh = __builtin_bit_cast(bf16x8, sh1);
                bf16x8 vm = __builtin_bit_cast(bf16x8, sm1);
                bf16x8 vl = __builtin_bit_cast(bf16x8, sl1);
                bf16x8 Bh = __builtin_bit_cast(bf16x8, bb[c][1]);
                bf16x8 Bm = __builtin_bit_cast(bf16x8, bb[c][5]);
                bf16x8 Bl = __builtin_bit_cast(bf16x8, bb[c][9]);
                acc0 = __builtin_amdgcn_mfma_f32_32x32x16_bf16(vh, Bh, acc0, 0, 0, 0);
                acc0 = __builtin_amdgcn_mfma_f32_32x32x16_bf16(vm, Bh, acc0, 0, 0, 0);
                acc0 = __builtin_amdgcn_mfma_f32_32x32x16_bf16(vl, Bh, acc0, 0, 0, 0);
                acc0 = __builtin_amdgcn_mfma_f32_32x32x16_bf16(vh, Bm, acc0, 0, 0, 0);
                acc0 = __builtin_amdgcn_mfma_f32_32x32x16_bf16(vm, Bm, acc0, 0, 0, 0);
                acc0 = __builtin_amdgcn_mfma_f32_32x32x16_bf16(vh, Bl, acc0, 0, 0, 0);
                Bh = __builtin_bit_cast(bf16x8, bb[c][3]);
                Bm = __builtin_bit_cast(bf16x8, bb[c][7]);
                Bl = __builtin_bit_cast(bf16x8, bb[c][11]);
                acc1 = __builtin_amdgcn_mfma_f32_32x32x16_bf16(vh, Bh, acc1, 0, 0, 0);
                acc1 = __builtin_amdgcn_mfma_f32_32x32x16_bf16(vm, Bh, acc1, 0, 0, 0);
                acc1 = __builtin_amdgcn_mfma_f32_32x32x16_bf16(vl, Bh, acc1, 0, 0, 0);
                acc1 = __builtin_amdgcn_mfma_f32_32x32x16_bf16(vh, Bm, acc1, 0, 0, 0);
                acc1 = __builtin_amdgcn_mfma_f32_32x32x16_bf16(vm, Bm, acc1, 0, 0, 0);
                acc1 = __builtin_amdgcn_mfma_f32_32x32x16_bf16(vh, Bl, acc1, 0, 0, 0);
            }
            __builtin_amdgcn_sched_barrier(0);
        }
    }

    // store: pre[h][t0+wv*32+row][e]; C/D: col=lane&31, row=(reg&3)+8*(reg>>2)+4*(lane>>5)
    float* dst = pre + (((size_t)h * N_TOK) + t0 + wv * 32) * NE + lr;
    #pragma unroll
    for (int q = 0; q < 4; ++q)
        #pragma unroll
        for (int j = 0; j < 4; ++j) {
            const int row = j + 8 * q + 4 * lkh;
            dst[(size_t)row * NE]      = acc0[q * 4 + j];
            dst[(size_t)row * NE + 32] = acc1[q * 4 + j];
        }
}

__global__ __launch_bounds__(256) void torus_ep(
    const float* __restrict__ pre, const float* __restrict__ bias,
    const float* __restrict__ cp, const float* __restrict__ dp,
    const float* __restrict__ a1p, const float* __restrict__ b1p,
    float* __restrict__ out, float* __restrict__ esum)
{
    __shared__ float stile[TBE][NE + 1];
    __shared__ float s_m[TBE], s_inv[TBE];

    const int tid = threadIdx.x;
    const int t0  = blockIdx.x * TBE;

    {
        const float c_ = *cp, d_ = *dp, a1_ = *a1p, b1_ = *b1p;
        const int tok = tid >> 2;
        const int e0  = (tid & 3) * 16;
        const float* px = pre + (size_t)(t0 + tok) * NE + e0;
        const float* py = pre + ((size_t)N_TOK + t0 + tok) * NE + e0;
        #pragma unroll
        for (int i = 0; i < 16; i += 4) {
            f32x4 xv = *(const f32x4*)(px + i);
            f32x4 yv = *(const f32x4*)(py + i);
            #pragma unroll
            for (int j = 0; j < 4; ++j) {
                int e = e0 + i + j;
                float x = tanhf(xv[j]) * 2.0f;
                float y = tanhf(yv[j]) * 2.0f;
                float xa = fabsf(x), ya = fabsf(y);
                float sc = (powf(xa, a1_) + powf(ya, b1_)) *
                           expf(-(powf(xa, c_) + powf(ya, d_))) + bias[e];
                stile[tok][e] = sc;
            }
        }
    }
    __syncthreads();

    if (tid < TBE) {
        const int t = tid;
        float bv[TOPK]; int bi[TOPK];
        #pragma unroll
        for (int p = 0; p < TOPK; ++p) {
            float best = -INFINITY; int besti = 0;
            for (int e = 0; e < NE; ++e) {
                float v = stile[t][e];
                bool taken = false;
                #pragma unroll
                for (int q = 0; q < p; ++q) taken = taken || (bi[q] == e);
                if (!taken && v > best) { best = v; besti = e; }  // strict > == lax.top_k tie-break
            }
            bv[p] = best; bi[p] = besti;
        }
        const float m = bv[0];
        float denom = 0.0f;
        for (int e = 0; e < NE; ++e) denom += expf(stile[t][e] - m);
        const float inv = 1.0f / denom;
        s_m[t] = m; s_inv[t] = inv;
        #pragma unroll
        for (int p = 0; p < TOPK; ++p) {
            out[OFF_TI + (size_t)(t0 + t) * TOPK + p] = (float)bi[p];
            out[OFF_TS + (size_t)(t0 + t) * TOPK + p] = bv[p];
        }
    }
    __syncthreads();

    if (tid < NE) {
        const int e = tid;
        float cs = 0.0f;
        for (int t = 0; t < TBE; ++t)
            cs += expf(stile[t][e] - s_m[t]) * s_inv[t];
        atomicAdd(&esum[e], cs);
    }

    for (int idx = tid; idx < TBE * NE; idx += 256)
        out[OFF_SC + (size_t)t0 * NE + idx] = stile[idx >> 6][idx & (NE - 1)];
}

__global__ __launch_bounds__(64) void torus_aux(const float* __restrict__ esum,
                                                float* __restrict__ out)
{
    const int e = threadIdx.x;
    float s = esum[e] * (1.0f / (float)N_TOK);
    float v = s * s;
    #pragma unroll
    for (int off = 32; off > 0; off >>= 1) v += __shfl_down(v, off);
    if (e == 0) out[OFF_AUX] = v * (float)NE;
}

extern "C" void kernel_launch(void* const* d_in, const int* in_sizes, int n_in,
                              void* d_out, int out_size, void* d_ws, size_t ws_size,
                              hipStream_t stream) {
    const float* u    = (const float*)d_in[0];
    const float* Ex   = (const float*)d_in[1];
    const float* Ey   = (const float*)d_in[2];
    const float* bias = (const float*)d_in[3];
    const float* cp   = (const float*)d_in[4];
    const float* dp   = (const float*)d_in[5];
    const float* a1p  = (const float*)d_in[6];
    const float* b1p  = (const float*)d_in[7];
    float* out  = (float*)d_out;
    __bf16* Bws = (__bf16*)d_ws;
    float* esum = (float*)((char*)d_ws + (size_t)BSPLIT_ELEMS * sizeof(__bf16));
    float* pre  = (float*)((char*)d_ws + PRE_BYTE_OFF);   // [2][N_TOK][64] fp32, 8 MB

    prep_B<<<128, 256, 0, stream>>>(Ex, Ey, Bws);
    hipMemsetAsync(esum, 0, NE * sizeof(float), stream);
    gemm_half<<<N_TOK / 128 * 2, 256, 0, stream>>>(u, Bws, pre);
    torus_ep<<<N_TOK / TBE, 256, 0, stream>>>(pre, bias, cp, dp, a1p, b1p, out, esum);
    torus_aux<<<1, 64, 0, stream>>>(esum, out);
}

// Round 14
// 120.645 us; speedup vs baseline: 2.1607x; 1.0567x over previous
//
#include <hip/hip_runtime.h>
#include <math.h>
#include <stdint.h>

#define N_TOK 16384
#define DM    4096
#define DH    2048
#define NE    64
#define TBE   64
#define TOPK  4
#define NST   32        // K=2048 per half / 64 per step

// out layout (all float32): topk_i [N,4] | topk_s [N,4] | scores [N,64] | aux_loss [1]
#define OFF_TI  0
#define OFF_TS  (N_TOK * TOPK)
#define OFF_SC  (N_TOK * TOPK * 2)
#define OFF_AUX (N_TOK * TOPK * 2 + N_TOK * NE)

typedef __attribute__((ext_vector_type(4)))  float  f32x4;
typedef __attribute__((ext_vector_type(16))) float  f32x16;
typedef __attribute__((ext_vector_type(8)))  __bf16 bf16x8;
typedef __attribute__((ext_vector_type(8)))  unsigned short u16x8;

// ws layout: Bws bf16 [0..1.5MB) | esum f32 | pre f32 [h2][N][64] @ 2MB (8MB)
#define BSPLIT_ELEMS (2 * 64 * 3 * 2 * 2 * 64 * 8)
#define PRE_BYTE_OFF (2u * 1024u * 1024u)

__device__ __forceinline__ void split3(float a, __bf16& h, __bf16& m, __bf16& l) {
    h = (__bf16)a;
    float r = a - (float)h;
    m = (__bf16)r;
    float r2 = r - (float)m;
    l = (__bf16)r2;
}

__device__ __forceinline__ void stage16(const float* g, void* l) {
    __builtin_amdgcn_global_load_lds(
        (const __attribute__((address_space(1))) unsigned int*)(uintptr_t)g,
        (__attribute__((address_space(3))) unsigned int*)(uintptr_t)l,
        16, 0, 0);
}

__device__ __forceinline__ void splitPair(const f32x4& lo, const f32x4& hi,
                                          u16x8& sh, u16x8& sm, u16x8& sl) {
    #pragma unroll
    for (int q = 0; q < 2; ++q)
        #pragma unroll
        for (int j = 0; j < 4; ++j) {
            float a = (q == 0 ? lo : hi)[j];
            unsigned h32 = __float_as_uint(a) & 0xFFFF0000u;
            float rr = a - __uint_as_float(h32);
            unsigned m32 = __float_as_uint(rr) & 0xFFFF0000u;
            float r2f = rr - __uint_as_float(m32);
            sh[q * 4 + j] = (unsigned short)(h32 >> 16);
            sm[q * 4 + j] = (unsigned short)(m32 >> 16);
            sl[q * 4 + j] = (unsigned short)(__float_as_uint(r2f) >> 16);
        }
}

// Fragment-major split B: byte addr(h,ks,sp,et,sk) = (h*64+ks)*12288 + (sp*4+et*2+sk)*1024 + lane*16
// Also zeroes esum (replaces the hipMemsetAsync dispatch).
__global__ __launch_bounds__(256) void prep_B(
    const float* __restrict__ Ex, const float* __restrict__ Ey,
    __bf16* __restrict__ Bws, float* __restrict__ esum)
{
    if (blockIdx.x == 0 && threadIdx.x < NE) esum[threadIdx.x] = 0.0f;
    const int t    = blockIdx.x * 256 + threadIdx.x;
    const int lane = t & 63;
    const int sk   = (t >> 6) & 1;
    const int et   = (t >> 7) & 1;
    const int ks   = (t >> 8) & 63;
    const int h    = (t >> 14) & 1;
    const float* E = h ? Ey : Ex;
    const int e  = et * 32 + (lane & 31);
    const int k0 = ks * 32 + sk * 16 + (lane >> 5) * 8;
    bf16x8 vh, vm, vl;
    #pragma unroll
    for (int j = 0; j < 8; ++j) {
        __bf16 hh, mm, ll;
        split3(E[(size_t)(k0 + j) * NE + e], hh, mm, ll);
        vh[j] = hh; vm[j] = mm; vl[j] = ll;
    }
    #pragma unroll
    for (int s = 0; s < 3; ++s) {
        size_t base = ((((((size_t)h * 64 + ks) * 3 + s) * 2 + et) * 2 + sk) * 64 + lane) * 8;
        *(bf16x8*)(Bws + base) = (s == 0) ? vh : (s == 1) ? vm : vl;
    }
}

// Block = 128 tok x one half; 4 waves, each 32 tok x 64 e x full K=2048.
// B(s) staged ONCE per block into LDS dbuf (latency off the MFMA path);
// A per-wave LDS ring. One raw s_barrier per step; consume path is pure LDS.
__global__ __launch_bounds__(256, 1) void gemm_half(
    const float* __restrict__ u, const __bf16* __restrict__ Bws,
    float* __restrict__ pre)
{
    __shared__ __align__(16) unsigned char aring[4][2][8192];   // [wave][slot][32 rows x 256B]
    __shared__ __align__(16) unsigned char bring[2][24576];     // [slot][24 frags x 1KB]

    const int tid  = threadIdx.x;
    const int lane = tid & 63;
    const int wv   = tid >> 6;           // 0..3 token quarter
    const int h    = blockIdx.x & 1;
    const int tile = blockIdx.x >> 1;
    const int t0   = tile * 128;
    const int lr   = lane & 31;          // MFMA A-row / B-col
    const int lkh  = lane >> 5;          // k-subgroup

    const float* abase = u + (size_t)(t0 + wv * 32) * DM + h * DH;
    // B source for this wave's 6 fragments: f = wv*6+j -> ks_off = wv>>1, fr = (wv&1)*6+j
    const char* bsrc = (const char*)Bws + (size_t)h * 64 * 12288
                     + (size_t)(wv >> 1) * 12288 + (size_t)((wv & 1) * 6) * 1024 + lane * 16;

    auto stageA = [&](int s, int slot) {
        unsigned char* d = &aring[wv][slot][0];
        const float* gs = abase + s * 64;
        #pragma unroll
        for (int i = 0; i < 8; ++i) {
            const int r = i * 4 + (lane >> 4);
            const int c = (lane & 15) ^ (r & 15);        // pre-swizzled source chunk
            stage16(gs + (size_t)r * DM + c * 4, d + i * 1024 + lane * 16);
        }
    };
    auto stageB = [&](int s, int slot) {
        unsigned char* d = &bring[slot][0] + (size_t)(wv * 6) * 1024;
        const char* srcs = bsrc + (size_t)(2 * s) * 12288;
        #pragma unroll
        for (int j = 0; j < 6; ++j)
            stage16((const float*)(srcs + j * 1024), d + j * 1024 + lane * 16);
    };

    f32x16 acc0 = {}, acc1 = {};
    const unsigned aB  = (unsigned)(uintptr_t)(void*)&aring[wv][0][0];
    const unsigned bB  = (unsigned)(uintptr_t)(void*)&bring[0][0];
    const unsigned swz = (unsigned)(lr & 15);

    stageA(0, 0); stageB(0, 0);

    #pragma unroll 1
    for (int s = 0; s < NST; ++s) {
        // stages for slot s were issued a full step ago; drain them, sync, stage next
        asm volatile("s_waitcnt vmcnt(0)" ::: "memory");
        __builtin_amdgcn_sched_barrier(0);
        __builtin_amdgcn_s_barrier();                  // raw barrier: no compiler drain
        __builtin_amdgcn_sched_barrier(0);
        if (s + 1 < NST) { stageA(s + 1, (s + 1) & 1); stageB(s + 1, (s + 1) & 1); }
        __builtin_amdgcn_sched_barrier(0);

        const unsigned as = aB + (unsigned)((s & 1) * 8192) + (unsigned)lr * 256;
        const unsigned bs = bB + (unsigned)((s & 1) * 24576);
        #pragma unroll
        for (int k2 = 0; k2 < 2; ++k2) {
            const unsigned c0 = (unsigned)(k2 * 8 + lkh * 2);
            unsigned a0 = as + (((c0    ) ^ swz) << 4);
            unsigned a1 = as + (((c0 + 1) ^ swz) << 4);
            unsigned a2 = as + (((c0 + 4) ^ swz) << 4);
            unsigned a3 = as + (((c0 + 5) ^ swz) << 4);
            f32x4 r0, r1, r2, r3;
            asm volatile(
                "ds_read_b128 %0, %4\n\t"
                "ds_read_b128 %1, %5\n\t"
                "ds_read_b128 %2, %6\n\t"
                "ds_read_b128 %3, %7"
                : "=&v"(r0), "=&v"(r1), "=&v"(r2), "=&v"(r3)
                : "v"(a0), "v"(a1), "v"(a2), "v"(a3));
            const unsigned bk = bs + (unsigned)(k2 * 12 * 1024) + (unsigned)lane * 16;
            f32x4 b0,b1,b2,b3,b4,b5,b6,b7,b8,b9,b10,b11;
            asm volatile(
                "ds_read_b128 %0, %12 offset:0\n\t"
                "ds_read_b128 %1, %12 offset:1024\n\t"
                "ds_read_b128 %2, %12 offset:2048\n\t"
                "ds_read_b128 %3, %12 offset:3072\n\t"
                "ds_read_b128 %4, %12 offset:4096\n\t"
                "ds_read_b128 %5, %12 offset:5120\n\t"
                "ds_read_b128 %6, %12 offset:6144\n\t"
                "ds_read_b128 %7, %12 offset:7168\n\t"
                "ds_read_b128 %8, %12 offset:8192\n\t"
                "ds_read_b128 %9, %12 offset:9216\n\t"
                "ds_read_b128 %10, %12 offset:10240\n\t"
                "ds_read_b128 %11, %12 offset:11264\n\t"
                "s_waitcnt lgkmcnt(0)"
                : "=&v"(b0), "=&v"(b1), "=&v"(b2), "=&v"(b3), "=&v"(b4), "=&v"(b5),
                  "=&v"(b6), "=&v"(b7), "=&v"(b8), "=&v"(b9), "=&v"(b10), "=&v"(b11)
                : "v"(bk));
            __builtin_amdgcn_sched_barrier(0);
            u16x8 sh0, sm0, sl0, sh1, sm1, sl1;
            splitPair(r0, r1, sh0, sm0, sl0);
            splitPair(r2, r3, sh1, sm1, sl1);
            __builtin_amdgcn_sched_barrier(0);
            // frag idx = sp*4 + et*2 + sk; acc0 = expert half 0, acc1 = half 1
            {
                bf16x8 vh = __builtin_bit_cast(bf16x8, sh0);
                bf16x8 vm = __builtin_bit_cast(bf16x8, sm0);
                bf16x8 vl = __builtin_bit_cast(bf16x8, sl0);
                bf16x8 Bh = __builtin_bit_cast(bf16x8, b0);
                bf16x8 Bm = __builtin_bit_cast(bf16x8, b4);
                bf16x8 Bl = __builtin_bit_cast(bf16x8, b8);
                acc0 = __builtin_amdgcn_mfma_f32_32x32x16_bf16(vh, Bh, acc0, 0, 0, 0);
                acc0 = __builtin_amdgcn_mfma_f32_32x32x16_bf16(vm, Bh, acc0, 0, 0, 0);
                acc0 = __builtin_amdgcn_mfma_f32_32x32x16_bf16(vl, Bh, acc0, 0, 0, 0);
                acc0 = __builtin_amdgcn_mfma_f32_32x32x16_bf16(vh, Bm, acc0, 0, 0, 0);
                acc0 = __builtin_amdgcn_mfma_f32_32x32x16_bf16(vm, Bm, acc0, 0, 0, 0);
                acc0 = __builtin_amdgcn_mfma_f32_32x32x16_bf16(vh, Bl, acc0, 0, 0, 0);
                Bh = __builtin_bit_cast(bf16x8, b2);
                Bm = __builtin_bit_cast(bf16x8, b6);
                Bl = __builtin_bit_cast(bf16x8, b10);
                acc1 = __builtin_amdgcn_mfma_f32_32x32x16_bf16(vh, Bh, acc1, 0, 0, 0);
                acc1 = __builtin_amdgcn_mfma_f32_32x32x16_bf16(vm, Bh, acc1, 0, 0, 0);
                acc1 = __builtin_amdgcn_mfma_f32_32x32x16_bf16(vl, Bh, acc1, 0, 0, 0);
                acc1 = __builtin_amdgcn_mfma_f32_32x32x16_bf16(vh, Bm, acc1, 0, 0, 0);
                acc1 = __builtin_amdgcn_mfma_f32_32x32x16_bf16(vm, Bm, acc1, 0, 0, 0);
                acc1 = __builtin_amdgcn_mfma_f32_32x32x16_bf16(vh, Bl, acc1, 0, 0, 0);
            }
            {
                bf16x8 vh = __builtin_bit_cast(bf16x8, sh1);
                bf16x8 vm = __builtin_bit_cast(bf16x8, sm1);
                bf16x8 vl = __builtin_bit_cast(bf16x8, sl1);
                bf16x8 Bh = __builtin_bit_cast(bf16x8, b1);
                bf16x8 Bm = __builtin_bit_cast(bf16x8, b5);
                bf16x8 Bl = __builtin_bit_cast(bf16x8, b9);
                acc0 = __builtin_amdgcn_mfma_f32_32x32x16_bf16(vh, Bh, acc0, 0, 0, 0);
                acc0 = __builtin_amdgcn_mfma_f32_32x32x16_bf16(vm, Bh, acc0, 0, 0, 0);
                acc0 = __builtin_amdgcn_mfma_f32_32x32x16_bf16(vl, Bh, acc0, 0, 0, 0);
                acc0 = __builtin_amdgcn_mfma_f32_32x32x16_bf16(vh, Bm, acc0, 0, 0, 0);
                acc0 = __builtin_amdgcn_mfma_f32_32x32x16_bf16(vm, Bm, acc0, 0, 0, 0);
                acc0 = __builtin_amdgcn_mfma_f32_32x32x16_bf16(vh, Bl, acc0, 0, 0, 0);
                Bh = __builtin_bit_cast(bf16x8, b3);
                Bm = __builtin_bit_cast(bf16x8, b7);
                Bl = __builtin_bit_cast(bf16x8, b11);
                acc1 = __builtin_amdgcn_mfma_f32_32x32x16_bf16(vh, Bh, acc1, 0, 0, 0);
                acc1 = __builtin_amdgcn_mfma_f32_32x32x16_bf16(vm, Bh, acc1, 0, 0, 0);
                acc1 = __builtin_amdgcn_mfma_f32_32x32x16_bf16(vl, Bh, acc1, 0, 0, 0);
                acc1 = __builtin_amdgcn_mfma_f32_32x32x16_bf16(vh, Bm, acc1, 0, 0, 0);
                acc1 = __builtin_amdgcn_mfma_f32_32x32x16_bf16(vm, Bm, acc1, 0, 0, 0);
                acc1 = __builtin_amdgcn_mfma_f32_32x32x16_bf16(vh, Bl, acc1, 0, 0, 0);
            }
            __builtin_amdgcn_sched_barrier(0);
        }
    }

    // store pre[h][t0+wv*32+row][e]; C/D: col=lane&31, row=(reg&3)+8*(reg>>2)+4*(lane>>5)
    float* dst = pre + (((size_t)h * N_TOK) + t0 + wv * 32) * NE + lr;
    #pragma unroll
    for (int q = 0; q < 4; ++q)
        #pragma unroll
        for (int j = 0; j < 4; ++j) {
            const int row = j + 8 * q + 4 * lkh;
            dst[(size_t)row * NE]      = acc0[q * 4 + j];
            dst[(size_t)row * NE + 32] = acc1[q * 4 + j];
        }
}

__global__ __launch_bounds__(256) void torus_ep(
    const float* __restrict__ pre, const float* __restrict__ bias,
    const float* __restrict__ cp, const float* __restrict__ dp,
    const float* __restrict__ a1p, const float* __restrict__ b1p,
    float* __restrict__ out, float* __restrict__ esum)
{
    __shared__ float stile[TBE][NE + 1];
    __shared__ float s_m[TBE], s_inv[TBE];

    const int tid = threadIdx.x;
    const int t0  = blockIdx.x * TBE;

    {
        const float c_ = *cp, d_ = *dp, a1_ = *a1p, b1_ = *b1p;
        const int tok = tid >> 2;
        const int e0  = (tid & 3) * 16;
        const float* px = pre + (size_t)(t0 + tok) * NE + e0;
        const float* py = pre + ((size_t)N_TOK + t0 + tok) * NE + e0;
        #pragma unroll
        for (int i = 0; i < 16; i += 4) {
            f32x4 xv = *(const f32x4*)(px + i);
            f32x4 yv = *(const f32x4*)(py + i);
            #pragma unroll
            for (int j = 0; j < 4; ++j) {
                int e = e0 + i + j;
                float x = tanhf(xv[j]) * 2.0f;
                float y = tanhf(yv[j]) * 2.0f;
                float xa = fabsf(x), ya = fabsf(y);
                float sc = (powf(xa, a1_) + powf(ya, b1_)) *
                           expf(-(powf(xa, c_) + powf(ya, d_))) + bias[e];
                stile[tok][e] = sc;
            }
        }
    }
    __syncthreads();

    if (tid < TBE) {
        const int t = tid;
        float bv[TOPK]; int bi[TOPK];
        #pragma unroll
        for (int p = 0; p < TOPK; ++p) {
            float best = -INFINITY; int besti = 0;
            for (int e = 0; e < NE; ++e) {
                float v = stile[t][e];
                bool taken = false;
                #pragma unroll
                for (int q = 0; q < p; ++q) taken = taken || (bi[q] == e);
                if (!taken && v > best) { best = v; besti = e; }  // strict > == lax.top_k tie-break
            }
            bv[p] = best; bi[p] = besti;
        }
        const float m = bv[0];
        float denom = 0.0f;
        for (int e = 0; e < NE; ++e) denom += expf(stile[t][e] - m);
        const float inv = 1.0f / denom;
        s_m[t] = m; s_inv[t] = inv;
        #pragma unroll
        for (int p = 0; p < TOPK; ++p) {
            out[OFF_TI + (size_t)(t0 + t) * TOPK + p] = (float)bi[p];
            out[OFF_TS + (size_t)(t0 + t) * TOPK + p] = bv[p];
        }
    }
    __syncthreads();

    if (tid < NE) {
        const int e = tid;
        float cs = 0.0f;
        for (int t = 0; t < TBE; ++t)
            cs += expf(stile[t][e] - s_m[t]) * s_inv[t];
        atomicAdd(&esum[e], cs);
    }

    for (int idx = tid; idx < TBE * NE; idx += 256)
        out[OFF_SC + (size_t)t0 * NE + idx] = stile[idx >> 6][idx & (NE - 1)];
}

__global__ __launch_bounds__(64) void torus_aux(const float* __restrict__ esum,
                                                float* __restrict__ out)
{
    const int e = threadIdx.x;
    float s = esum[e] * (1.0f / (float)N_TOK);
    float v = s * s;
    #pragma unroll
    for (int off = 32; off > 0; off >>= 1) v += __shfl_down(v, off);
    if (e == 0) out[OFF_AUX] = v * (float)NE;
}

extern "C" void kernel_launch(void* const* d_in, const int* in_sizes, int n_in,
                              void* d_out, int out_size, void* d_ws, size_t ws_size,
                              hipStream_t stream) {
    const float* u    = (const float*)d_in[0];
    const float* Ex   = (const float*)d_in[1];
    const float* Ey   = (const float*)d_in[2];
    const float* bias = (const float*)d_in[3];
    const float* cp   = (const float*)d_in[4];
    const float* dp   = (const float*)d_in[5];
    const float* a1p  = (const float*)d_in[6];
    const float* b1p  = (const float*)d_in[7];
    float* out  = (float*)d_out;
    __bf16* Bws = (__bf16*)d_ws;
    float* esum = (float*)((char*)d_ws + (size_t)BSPLIT_ELEMS * sizeof(__bf16));
    float* pre  = (float*)((char*)d_ws + PRE_BYTE_OFF);   // [2][N_TOK][64] fp32, 8 MB

    prep_B<<<128, 256, 0, stream>>>(Ex, Ey, Bws, esum);
    gemm_half<<<N_TOK / 128 * 2, 256, 0, stream>>>(u, Bws, pre);
    torus_ep<<<N_TOK / TBE, 256, 0, stream>>>(pre, bias, cp, dp, a1p, b1p, out, esum);
    torus_aux<<<1, 64, 0, stream>>>(esum, out);
}

// Round 15
// 113.982 us; speedup vs baseline: 2.2870x; 1.0585x over previous
//
#include <hip/hip_runtime.h>
#include <math.h>
#include <stdint.h>

#define N_TOK 16384
#define DM    4096
#define DH    2048
#define NE    64
#define TBE   64
#define TOPK  4
#define NST   32        // K=2048 per half / 64 per step

// out layout (all float32): topk_i [N,4] | topk_s [N,4] | scores [N,64] | aux_loss [1]
#define OFF_TI  0
#define OFF_TS  (N_TOK * TOPK)
#define OFF_SC  (N_TOK * TOPK * 2)
#define OFF_AUX (N_TOK * TOPK * 2 + N_TOK * NE)

typedef __attribute__((ext_vector_type(4)))  float  f32x4;
typedef __attribute__((ext_vector_type(16))) float  f32x16;
typedef __attribute__((ext_vector_type(8)))  __bf16 bf16x8;
typedef __attribute__((ext_vector_type(8)))  unsigned short u16x8;

// ws layout: Bws bf16 [0..1.5MB) | esum f32 | pre f32 [h2][N][64] @ 2MB (8MB)
#define BSPLIT_ELEMS (2 * 64 * 3 * 2 * 2 * 64 * 8)
#define PRE_BYTE_OFF (2u * 1024u * 1024u)

__device__ __forceinline__ void split3(float a, __bf16& h, __bf16& m, __bf16& l) {
    h = (__bf16)a;
    float r = a - (float)h;
    m = (__bf16)r;
    float r2 = r - (float)m;
    l = (__bf16)r2;
}

__device__ __forceinline__ void stage16(const float* g, void* l) {
    __builtin_amdgcn_global_load_lds(
        (const __attribute__((address_space(1))) unsigned int*)(uintptr_t)g,
        (__attribute__((address_space(3))) unsigned int*)(uintptr_t)l,
        16, 0, 0);
}

__device__ __forceinline__ void splitPair(const f32x4& lo, const f32x4& hi,
                                          u16x8& sh, u16x8& sm, u16x8& sl) {
    #pragma unroll
    for (int q = 0; q < 2; ++q)
        #pragma unroll
        for (int j = 0; j < 4; ++j) {
            float a = (q == 0 ? lo : hi)[j];
            unsigned h32 = __float_as_uint(a) & 0xFFFF0000u;
            float rr = a - __uint_as_float(h32);
            unsigned m32 = __float_as_uint(rr) & 0xFFFF0000u;
            float r2f = rr - __uint_as_float(m32);
            sh[q * 4 + j] = (unsigned short)(h32 >> 16);
            sm[q * 4 + j] = (unsigned short)(m32 >> 16);
            sl[q * 4 + j] = (unsigned short)(__float_as_uint(r2f) >> 16);
        }
}

// Fragment-major split B: byte addr(h,ks,sp,et,sk) = (h*64+ks)*12288 + (sp*4+et*2+sk)*1024 + lane*16
// Also zeroes esum (replaces the hipMemsetAsync dispatch).
__global__ __launch_bounds__(256) void prep_B(
    const float* __restrict__ Ex, const float* __restrict__ Ey,
    __bf16* __restrict__ Bws, float* __restrict__ esum)
{
    if (blockIdx.x == 0 && threadIdx.x < NE) esum[threadIdx.x] = 0.0f;
    const int t    = blockIdx.x * 256 + threadIdx.x;
    const int lane = t & 63;
    const int sk   = (t >> 6) & 1;
    const int et   = (t >> 7) & 1;
    const int ks   = (t >> 8) & 63;
    const int h    = (t >> 14) & 1;
    const float* E = h ? Ey : Ex;
    const int e  = et * 32 + (lane & 31);
    const int k0 = ks * 32 + sk * 16 + (lane >> 5) * 8;
    bf16x8 vh, vm, vl;
    #pragma unroll
    for (int j = 0; j < 8; ++j) {
        __bf16 hh, mm, ll;
        split3(E[(size_t)(k0 + j) * NE + e], hh, mm, ll);
        vh[j] = hh; vm[j] = mm; vl[j] = ll;
    }
    #pragma unroll
    for (int s = 0; s < 3; ++s) {
        size_t base = ((((((size_t)h * 64 + ks) * 3 + s) * 2 + et) * 2 + sk) * 64 + lane) * 8;
        *(bf16x8*)(Bws + base) = (s == 0) ? vh : (s == 1) ? vm : vl;
    }
}

// Block = 128 tok x one half; 4 waves, each 32 tok x 64 e x full K=2048.
// B(s) LDS dbuf (block-shared), A per-wave 3-deep LDS ring staged 2 ahead.
// Counted vmcnt(8) per step (T4): never drain the pipeline.
__global__ __launch_bounds__(256, 1) void gemm_half(
    const float* __restrict__ u, const __bf16* __restrict__ Bws,
    float* __restrict__ pre)
{
    __shared__ __align__(16) unsigned char aring[4][3][8192];   // [wave][slot][32 rows x 256B]
    __shared__ __align__(16) unsigned char bring[2][24576];     // [slot][24 frags x 1KB]

    const int tid  = threadIdx.x;
    const int lane = tid & 63;
    const int wv   = tid >> 6;           // 0..3 token quarter
    const int h    = blockIdx.x & 1;
    const int tile = blockIdx.x >> 1;
    const int t0   = tile * 128;
    const int lr   = lane & 31;          // MFMA A-row / B-col
    const int lkh  = lane >> 5;          // k-subgroup

    const float* abase = u + (size_t)(t0 + wv * 32) * DM + h * DH;
    // B source for this wave's 6 fragments of each step
    const char* bsrc = (const char*)Bws + (size_t)h * 64 * 12288
                     + (size_t)(wv >> 1) * 12288 + (size_t)((wv & 1) * 6) * 1024 + lane * 16;

    auto stageA = [&](int s, int slot) {
        unsigned char* d = &aring[wv][slot][0];
        const float* gs = abase + s * 64;
        #pragma unroll
        for (int i = 0; i < 8; ++i) {
            const int r = i * 4 + (lane >> 4);
            const int c = (lane & 15) ^ (r & 15);        // pre-swizzled source chunk
            stage16(gs + (size_t)r * DM + c * 4, d + i * 1024 + lane * 16);
        }
    };
    auto stageB = [&](int s, int slot) {
        unsigned char* d = &bring[slot][0] + (size_t)(wv * 6) * 1024;
        const char* srcs = bsrc + (size_t)(2 * s) * 12288;
        #pragma unroll
        for (int j = 0; j < 6; ++j)
            stage16((const float*)(srcs + j * 1024), d + j * 1024 + lane * 16);
    };

    f32x16 acc0 = {}, acc1 = {};
    const unsigned aB  = (unsigned)(uintptr_t)(void*)&aring[wv][0][0];
    const unsigned bB  = (unsigned)(uintptr_t)(void*)&bring[0][0];
    const unsigned swz = (unsigned)(lr & 15);

    // prologue: B(0) [6], A(0) [8], A(1) [8]  (oldest-first for the vmcnt math)
    stageB(0, 0); stageA(0, 0); stageA(1, 1);

    #pragma unroll 1
    for (int s = 0; s < NST; ++s) {
        // Counted wait (T4): newer-than-{A(s),B(s)} = A(s+1)'s 8 loads (if issued).
        // A(s) was issued 2 periods ago, B(s) 1 period ago -> near-no-op in steady state.
        if (s < NST - 1) asm volatile("s_waitcnt vmcnt(8)" ::: "memory");
        else             asm volatile("s_waitcnt vmcnt(0)" ::: "memory");
        __builtin_amdgcn_sched_barrier(0);
        __builtin_amdgcn_s_barrier();                  // raw barrier: no compiler drain
        __builtin_amdgcn_sched_barrier(0);
        // issue AFTER the barrier (cross-wave B WAR safe: all waves done with prev compute)
        if (s + 1 < NST) stageB(s + 1, (s + 1) & 1);
        if (s + 2 < NST) stageA(s + 2, (s + 2) % 3);
        __builtin_amdgcn_sched_barrier(0);

        const unsigned as = aB + (unsigned)((s % 3) * 8192) + (unsigned)lr * 256;
        const unsigned bs = bB + (unsigned)((s & 1) * 24576);
        #pragma unroll
        for (int k2 = 0; k2 < 2; ++k2) {
            const unsigned c0 = (unsigned)(k2 * 8 + lkh * 2);
            unsigned a0 = as + (((c0    ) ^ swz) << 4);
            unsigned a1 = as + (((c0 + 1) ^ swz) << 4);
            unsigned a2 = as + (((c0 + 4) ^ swz) << 4);
            unsigned a3 = as + (((c0 + 5) ^ swz) << 4);
            f32x4 r0, r1, r2, r3;
            asm volatile(
                "ds_read_b128 %0, %4\n\t"
                "ds_read_b128 %1, %5\n\t"
                "ds_read_b128 %2, %6\n\t"
                "ds_read_b128 %3, %7"
                : "=&v"(r0), "=&v"(r1), "=&v"(r2), "=&v"(r3)
                : "v"(a0), "v"(a1), "v"(a2), "v"(a3));
            const unsigned bk = bs + (unsigned)(k2 * 12 * 1024) + (unsigned)lane * 16;
            f32x4 b0,b1,b2,b3,b4,b5,b6,b7,b8,b9,b10,b11;
            asm volatile(
                "ds_read_b128 %0, %12 offset:0\n\t"
                "ds_read_b128 %1, %12 offset:1024\n\t"
                "ds_read_b128 %2, %12 offset:2048\n\t"
                "ds_read_b128 %3, %12 offset:3072\n\t"
                "ds_read_b128 %4, %12 offset:4096\n\t"
                "ds_read_b128 %5, %12 offset:5120\n\t"
                "ds_read_b128 %6, %12 offset:6144\n\t"
                "ds_read_b128 %7, %12 offset:7168\n\t"
                "ds_read_b128 %8, %12 offset:8192\n\t"
                "ds_read_b128 %9, %12 offset:9216\n\t"
                "ds_read_b128 %10, %12 offset:10240\n\t"
                "ds_read_b128 %11, %12 offset:11264\n\t"
                "s_waitcnt lgkmcnt(0)"
                : "=&v"(b0), "=&v"(b1), "=&v"(b2), "=&v"(b3), "=&v"(b4), "=&v"(b5),
                  "=&v"(b6), "=&v"(b7), "=&v"(b8), "=&v"(b9), "=&v"(b10), "=&v"(b11)
                : "v"(bk));
            __builtin_amdgcn_sched_barrier(0);
            u16x8 sh0, sm0, sl0, sh1, sm1, sl1;
            splitPair(r0, r1, sh0, sm0, sl0);
            splitPair(r2, r3, sh1, sm1, sl1);
            __builtin_amdgcn_sched_barrier(0);
            // frag idx = sp*4 + et*2 + sk; acc0 = expert half 0, acc1 = half 1
            {
                bf16x8 vh = __builtin_bit_cast(bf16x8, sh0);
                bf16x8 vm = __builtin_bit_cast(bf16x8, sm0);
                bf16x8 vl = __builtin_bit_cast(bf16x8, sl0);
                bf16x8 Bh = __builtin_bit_cast(bf16x8, b0);
                bf16x8 Bm = __builtin_bit_cast(bf16x8, b4);
                bf16x8 Bl = __builtin_bit_cast(bf16x8, b8);
                acc0 = __builtin_amdgcn_mfma_f32_32x32x16_bf16(vh, Bh, acc0, 0, 0, 0);
                acc0 = __builtin_amdgcn_mfma_f32_32x32x16_bf16(vm, Bh, acc0, 0, 0, 0);
                acc0 = __builtin_amdgcn_mfma_f32_32x32x16_bf16(vl, Bh, acc0, 0, 0, 0);
                acc0 = __builtin_amdgcn_mfma_f32_32x32x16_bf16(vh, Bm, acc0, 0, 0, 0);
                acc0 = __builtin_amdgcn_mfma_f32_32x32x16_bf16(vm, Bm, acc0, 0, 0, 0);
                acc0 = __builtin_amdgcn_mfma_f32_32x32x16_bf16(vh, Bl, acc0, 0, 0, 0);
                Bh = __builtin_bit_cast(bf16x8, b2);
                Bm = __builtin_bit_cast(bf16x8, b6);
                Bl = __builtin_bit_cast(bf16x8, b10);
                acc1 = __builtin_amdgcn_mfma_f32_32x32x16_bf16(vh, Bh, acc1, 0, 0, 0);
                acc1 = __builtin_amdgcn_mfma_f32_32x32x16_bf16(vm, Bh, acc1, 0, 0, 0);
                acc1 = __builtin_amdgcn_mfma_f32_32x32x16_bf16(vl, Bh, acc1, 0, 0, 0);
                acc1 = __builtin_amdgcn_mfma_f32_32x32x16_bf16(vh, Bm, acc1, 0, 0, 0);
                acc1 = __builtin_amdgcn_mfma_f32_32x32x16_bf16(vm, Bm, acc1, 0, 0, 0);
                acc1 = __builtin_amdgcn_mfma_f32_32x32x16_bf16(vh, Bl, acc1, 0, 0, 0);
            }
            {
                bf16x8 vh = __builtin_bit_cast(bf16x8, sh1);
                bf16x8 vm = __builtin_bit_cast(bf16x8, sm1);
                bf16x8 vl = __builtin_bit_cast(bf16x8, sl1);
                bf16x8 Bh = __builtin_bit_cast(bf16x8, b1);
                bf16x8 Bm = __builtin_bit_cast(bf16x8, b5);
                bf16x8 Bl = __builtin_bit_cast(bf16x8, b9);
                acc0 = __builtin_amdgcn_mfma_f32_32x32x16_bf16(vh, Bh, acc0, 0, 0, 0);
                acc0 = __builtin_amdgcn_mfma_f32_32x32x16_bf16(vm, Bh, acc0, 0, 0, 0);
                acc0 = __builtin_amdgcn_mfma_f32_32x32x16_bf16(vl, Bh, acc0, 0, 0, 0);
                acc0 = __builtin_amdgcn_mfma_f32_32x32x16_bf16(vh, Bm, acc0, 0, 0, 0);
                acc0 = __builtin_amdgcn_mfma_f32_32x32x16_bf16(vm, Bm, acc0, 0, 0, 0);
                acc0 = __builtin_amdgcn_mfma_f32_32x32x16_bf16(vh, Bl, acc0, 0, 0, 0);
                Bh = __builtin_bit_cast(bf16x8, b3);
                Bm = __builtin_bit_cast(bf16x8, b7);
                Bl = __builtin_bit_cast(bf16x8, b11);
                acc1 = __builtin_amdgcn_mfma_f32_32x32x16_bf16(vh, Bh, acc1, 0, 0, 0);
                acc1 = __builtin_amdgcn_mfma_f32_32x32x16_bf16(vm, Bh, acc1, 0, 0, 0);
                acc1 = __builtin_amdgcn_mfma_f32_32x32x16_bf16(vl, Bh, acc1, 0, 0, 0);
                acc1 = __builtin_amdgcn_mfma_f32_32x32x16_bf16(vh, Bm, acc1, 0, 0, 0);
                acc1 = __builtin_amdgcn_mfma_f32_32x32x16_bf16(vm, Bm, acc1, 0, 0, 0);
                acc1 = __builtin_amdgcn_mfma_f32_32x32x16_bf16(vh, Bl, acc1, 0, 0, 0);
            }
            __builtin_amdgcn_sched_barrier(0);
        }
    }

    // store pre[h][t0+wv*32+row][e]; C/D: col=lane&31, row=(reg&3)+8*(reg>>2)+4*(lane>>5)
    float* dst = pre + (((size_t)h * N_TOK) + t0 + wv * 32) * NE + lr;
    #pragma unroll
    for (int q = 0; q < 4; ++q)
        #pragma unroll
        for (int j = 0; j < 4; ++j) {
            const int row = j + 8 * q + 4 * lkh;
            dst[(size_t)row * NE]      = acc0[q * 4 + j];
            dst[(size_t)row * NE + 32] = acc1[q * 4 + j];
        }
}

__global__ __launch_bounds__(256) void torus_ep(
    const float* __restrict__ pre, const float* __restrict__ bias,
    const float* __restrict__ cp, const float* __restrict__ dp,
    const float* __restrict__ a1p, const float* __restrict__ b1p,
    float* __restrict__ out, float* __restrict__ esum)
{
    __shared__ float stile[TBE][NE + 1];
    __shared__ float s_m[TBE], s_inv[TBE];

    const int tid = threadIdx.x;
    const int t0  = blockIdx.x * TBE;

    {
        const float c_ = *cp, d_ = *dp, a1_ = *a1p, b1_ = *b1p;
        const int tok = tid >> 2;
        const int e0  = (tid & 3) * 16;
        const float* px = pre + (size_t)(t0 + tok) * NE + e0;
        const float* py = pre + ((size_t)N_TOK + t0 + tok) * NE + e0;
        #pragma unroll
        for (int i = 0; i < 16; i += 4) {
            f32x4 xv = *(const f32x4*)(px + i);
            f32x4 yv = *(const f32x4*)(py + i);
            #pragma unroll
            for (int j = 0; j < 4; ++j) {
                int e = e0 + i + j;
                float x = tanhf(xv[j]) * 2.0f;
                float y = tanhf(yv[j]) * 2.0f;
                float xa = fabsf(x), ya = fabsf(y);
                float sc = (powf(xa, a1_) + powf(ya, b1_)) *
                           expf(-(powf(xa, c_) + powf(ya, d_))) + bias[e];
                stile[tok][e] = sc;
            }
        }
    }
    __syncthreads();

    if (tid < TBE) {
        const int t = tid;
        float bv[TOPK]; int bi[TOPK];
        #pragma unroll
        for (int p = 0; p < TOPK; ++p) {
            float best = -INFINITY; int besti = 0;
            for (int e = 0; e < NE; ++e) {
                float v = stile[t][e];
                bool taken = false;
                #pragma unroll
                for (int q = 0; q < p; ++q) taken = taken || (bi[q] == e);
                if (!taken && v > best) { best = v; besti = e; }  // strict > == lax.top_k tie-break
            }
            bv[p] = best; bi[p] = besti;
        }
        const float m = bv[0];
        float denom = 0.0f;
        for (int e = 0; e < NE; ++e) denom += expf(stile[t][e] - m);
        const float inv = 1.0f / denom;
        s_m[t] = m; s_inv[t] = inv;
        #pragma unroll
        for (int p = 0; p < TOPK; ++p) {
            out[OFF_TI + (size_t)(t0 + t) * TOPK + p] = (float)bi[p];
            out[OFF_TS + (size_t)(t0 + t) * TOPK + p] = bv[p];
        }
    }
    __syncthreads();

    if (tid < NE) {
        const int e = tid;
        float cs = 0.0f;
        for (int t = 0; t < TBE; ++t)
            cs += expf(stile[t][e] - s_m[t]) * s_inv[t];
        atomicAdd(&esum[e], cs);
    }

    for (int idx = tid; idx < TBE * NE; idx += 256)
        out[OFF_SC + (size_t)t0 * NE + idx] = stile[idx >> 6][idx & (NE - 1)];
}

__global__ __launch_bounds__(64) void torus_aux(const float* __restrict__ esum,
                                                float* __restrict__ out)
{
    const int e = threadIdx.x;
    float s = esum[e] * (1.0f / (float)N_TOK);
    float v = s * s;
    #pragma unroll
    for (int off = 32; off > 0; off >>= 1) v += __shfl_down(v, off);
    if (e == 0) out[OFF_AUX] = v * (float)NE;
}

extern "C" void kernel_launch(void* const* d_in, const int* in_sizes, int n_in,
                              void* d_out, int out_size, void* d_ws, size_t ws_size,
                              hipStream_t stream) {
    const float* u    = (const float*)d_in[0];
    const float* Ex   = (const float*)d_in[1];
    const float* Ey   = (const float*)d_in[2];
    const float* bias = (const float*)d_in[3];
    const float* cp   = (const float*)d_in[4];
    const float* dp   = (const float*)d_in[5];
    const float* a1p  = (const float*)d_in[6];
    const float* b1p  = (const float*)d_in[7];
    float* out  = (float*)d_out;
    __bf16* Bws = (__bf16*)d_ws;
    float* esum = (float*)((char*)d_ws + (size_t)BSPLIT_ELEMS * sizeof(__bf16));
    float* pre  = (float*)((char*)d_ws + PRE_BYTE_OFF);   // [2][N_TOK][64] fp32, 8 MB

    prep_B<<<128, 256, 0, stream>>>(Ex, Ey, Bws, esum);
    gemm_half<<<N_TOK / 128 * 2, 256, 0, stream>>>(u, Bws, pre);
    torus_ep<<<N_TOK / TBE, 256, 0, stream>>>(pre, bias, cp, dp, a1p, b1p, out, esum);
    torus_aux<<<1, 64, 0, stream>>>(esum, out);
}